// Round 5
// baseline (498.298 us; speedup 1.0000x reference)
//
#include <hip/hip_runtime.h>
#include <math.h>

#define LAMBDA_INIT_F 0.7836057665316245f
#define ONE_MINUS_LI  0.2163942334683755f

typedef unsigned short ushort_t;
typedef unsigned int   uint32;
typedef unsigned long long u64;
typedef __attribute__((ext_vector_type(8))) short short8;
typedef __attribute__((ext_vector_type(4))) float f32x4;

// float -> bf16 (RNE)
__device__ __forceinline__ ushort_t f2bf(float f) {
    union { float f; uint32 u; } x; x.f = f;
    uint32 r = (x.u + 0x7fffu + ((x.u >> 16) & 1u)) >> 16;
    return (ushort_t)r;
}

// async global->LDS, 16B per lane. lds must be wave-uniform base; HW adds lane*16.
__device__ __forceinline__ void gld16(ushort_t* lds, const ushort_t* g) {
    __builtin_amdgcn_global_load_lds(
        (const __attribute__((address_space(1))) uint32*)g,
        (__attribute__((address_space(3))) uint32*)lds,
        16, 0, 0);
}

// ---------------------------------------------------------------------------
__global__ __launch_bounds__(64) void lambda_kernel(
    const float* __restrict__ lq1, const float* __restrict__ lk1,
    const float* __restrict__ lq2, const float* __restrict__ lk2,
    float* __restrict__ lam)
{
    int l = threadIdx.x;
    float p1 = lq1[l] * lk1[l];
    float p2 = lq2[l] * lk2[l];
    for (int off = 32; off; off >>= 1) {
        p1 += __shfl_down(p1, off);
        p2 += __shfl_down(p2, off);
    }
    if (l == 0) lam[0] = expf(p1) - expf(p2) + LAMBDA_INIT_F;
}

// g[j] = irfft(gaussian filter)[tau=j-64], j in [0,129). Parallel k-sum.
__global__ __launch_bounds__(256) void gfilt_kernel(float* __restrict__ g)
{
    __shared__ float red[4];
    const int j = blockIdx.x;            // 0..128
    int tau = j - 64;
    int ta = tau < 0 ? -tau : tau;       // cos is even
    const int tid = threadIdx.x;
    float acc = 0.0f;
    for (int k = tid; k <= 1024; k += 256) {
        float w = (k == 0 || k == 1024) ? 1.0f : 2.0f;
        float r = (float)k * (1.0f / 153.6f);
        float f = expf(-0.5f * r * r);
        int m = (k * ta) & 2047;
        float ang = (float)m * 3.0679615757712823e-3f;
        acc += w * f * cosf(ang);
    }
    for (int off = 32; off; off >>= 1) acc += __shfl_down(acc, off);
    if ((tid & 63) == 0) red[tid >> 6] = acc;
    __syncthreads();
    if (tid == 0)
        g[j] = (red[0] + red[1] + red[2] + red[3]) * (1.0f / 2048.0f);
}

// rotary tables: ct/st[t*32 + i] = cos/sin(t * 10000^(-i/32))
__global__ __launch_bounds__(256) void rottab(float* __restrict__ ct, float* __restrict__ st)
{
    int id = blockIdx.x * 256 + threadIdx.x;
    int t = id >> 5, i = id & 31;
    double inv = exp(-0.28782313662425575 * (double)i);
    double a = (double)t * inv;
    ct[id] = (float)cos(a);
    st[id] = (float)sin(a);
}

// fp32 -> bf16 elementwise (8/thread)
__global__ __launch_bounds__(256) void cvt_bf16(const float* __restrict__ s, ushort_t* __restrict__ d)
{
    int i = (blockIdx.x * 256 + threadIdx.x) * 8;
    float4 a = *(const float4*)(s + i);
    float4 b = *(const float4*)(s + i + 4);
    uint4 pk;
    pk.x = (uint32)f2bf(a.x) | ((uint32)f2bf(a.y) << 16);
    pk.y = (uint32)f2bf(a.z) | ((uint32)f2bf(a.w) << 16);
    pk.z = (uint32)f2bf(b.x) | ((uint32)f2bf(b.y) << 16);
    pk.w = (uint32)f2bf(b.z) | ((uint32)f2bf(b.w) << 16);
    *(uint4*)(d + i) = pk;
}

// Transpose W[k][n] fp32 -> WT[n'][k] bf16. For z<2 (Wq,Wk) permute n within each
// 64-col head2 group: n' = head2*64 + (d&1)*32 + (d>>1)  (de-interleave rotary pairs)
__global__ __launch_bounds__(256) void wtrans(
    const float* __restrict__ Wq, const float* __restrict__ Wk,
    const float* __restrict__ Wv, const float* __restrict__ Wo,
    ushort_t* __restrict__ Tq, ushort_t* __restrict__ Tk,
    ushort_t* __restrict__ Tv, ushort_t* __restrict__ To)
{
    int z = blockIdx.z;
    const float* S = (z == 0) ? Wq : (z == 1) ? Wk : (z == 2) ? Wv : Wo;
    ushort_t* Dt = (z == 0) ? Tq : (z == 1) ? Tk : (z == 2) ? Tv : To;
    bool perm = (z < 2);
    __shared__ float Ls[64 * 65];
    const int tid = threadIdx.x;
    const int n0 = blockIdx.x * 64, k0 = blockIdx.y * 64;
    #pragma unroll
    for (int it = 0; it < 4; ++it) {
        int kk = it * 16 + (tid >> 4);
        int nn = (tid & 15) * 4;
        float4 v = *(const float4*)(S + (size_t)(k0 + kk) * 2048 + n0 + nn);
        Ls[(nn + 0) * 65 + kk] = v.x;
        Ls[(nn + 1) * 65 + kk] = v.y;
        Ls[(nn + 2) * 65 + kk] = v.z;
        Ls[(nn + 3) * 65 + kk] = v.w;
    }
    __syncthreads();
    int nl = tid >> 2, kc = (tid & 3) * 16;
    int ng = n0 + nl;
    int nd = perm ? ((ng & ~63) | ((ng & 1) << 5) | ((ng & 63) >> 1)) : ng;
    uint4 p0, p1;
    const float* row = Ls + nl * 65 + kc;
    p0.x = (uint32)f2bf(row[0])  | ((uint32)f2bf(row[1])  << 16);
    p0.y = (uint32)f2bf(row[2])  | ((uint32)f2bf(row[3])  << 16);
    p0.z = (uint32)f2bf(row[4])  | ((uint32)f2bf(row[5])  << 16);
    p0.w = (uint32)f2bf(row[6])  | ((uint32)f2bf(row[7])  << 16);
    p1.x = (uint32)f2bf(row[8])  | ((uint32)f2bf(row[9])  << 16);
    p1.y = (uint32)f2bf(row[10]) | ((uint32)f2bf(row[11]) << 16);
    p1.z = (uint32)f2bf(row[12]) | ((uint32)f2bf(row[13]) << 16);
    p1.w = (uint32)f2bf(row[14]) | ((uint32)f2bf(row[15]) << 16);
    *(uint4*)(Dt + (size_t)nd * 2048 + k0 + kc) = p0;
    *(uint4*)(Dt + (size_t)nd * 2048 + k0 + kc + 8) = p1;
}

// ---------------------------------------------------------------------------
// Fused QKV GEMM: C = qb(2048x2048) * WT^T where WT = [WqT;WkT;WvT] (6144x2048).
// Epilogue by n-region: 0 -> rotary -> q1/q2, 1 -> rotary -> k1/k2, 2 -> V^T.
__global__ __launch_bounds__(256) void gemm_qkv(
    const ushort_t* __restrict__ A, const ushort_t* __restrict__ WT,
    ushort_t* __restrict__ q1, ushort_t* __restrict__ q2,
    ushort_t* __restrict__ k1, ushort_t* __restrict__ k2,
    ushort_t* __restrict__ v1T, ushort_t* __restrict__ v2T,
    const float* __restrict__ ctab, const float* __restrict__ stab)
{
    __shared__ ushort_t As[8192];
    __shared__ ushort_t Bs[8192];
    const int tid = threadIdx.x;
    const int w = tid >> 6, lane = tid & 63;
    const int quad = lane >> 4, l15 = lane & 15;
    const int wr = w >> 1, wc = w & 1;
    const int rb = blockIdx.y * 128, cb = blockIdx.x * 128;

    f32x4 acc[4][4];
    #pragma unroll
    for (int i = 0; i < 4; ++i)
        #pragma unroll
        for (int j = 0; j < 4; ++j) acc[i][j] = (f32x4)0.0f;

    for (int k0 = 0; k0 < 2048; k0 += 64) {
        #pragma unroll
        for (int u = 0; u < 4; ++u) {
            int off = (w * 4 + u) * 512;
            int Lc = (off >> 3) + lane;
            int row = Lc >> 3, cc = (Lc & 7) ^ (row & 7);
            gld16(As + off, A + (size_t)(rb + row) * 2048 + k0 + cc * 8);
            gld16(Bs + off, WT + (size_t)(cb + row) * 2048 + k0 + cc * 8);
        }
        __syncthreads();
        #pragma unroll
        for (int ks = 0; ks < 2; ++ks) {
            short8 af[4], bfr[4];
            #pragma unroll
            for (int mi = 0; mi < 4; ++mi) {
                int r = wr * 64 + mi * 16 + l15;
                af[mi] = *(const short8*)(As + r * 64 + ((ks * 4 + quad) ^ (r & 7)) * 8);
            }
            #pragma unroll
            for (int nj = 0; nj < 4; ++nj) {
                int r = wc * 64 + nj * 16 + l15;
                bfr[nj] = *(const short8*)(Bs + r * 64 + ((ks * 4 + quad) ^ (r & 7)) * 8);
            }
            #pragma unroll
            for (int mi = 0; mi < 4; ++mi)
                #pragma unroll
                for (int nj = 0; nj < 4; ++nj)
                    acc[mi][nj] = __builtin_amdgcn_mfma_f32_16x16x32_bf16(
                        af[mi], bfr[nj], acc[mi][nj], 0, 0, 0);
        }
        __syncthreads();
    }

    const int region = cb >> 11;         // 0=Q, 1=K, 2=V
    const int nloc = cb & 2047;
    if (region < 2) {
        int head2 = (nloc + wc * 64) >> 6;
        ushort_t* b1 = region ? k1 : q1;
        ushort_t* b2 = region ? k2 : q2;
        ushort_t* dst = ((head2 & 1) ? b2 : b1) + (size_t)(head2 >> 1) * 2048 * 64;
        #pragma unroll
        for (int mi = 0; mi < 4; ++mi)
            #pragma unroll
            for (int r = 0; r < 4; ++r) {
                int t = rb + wr * 64 + mi * 16 + quad * 4 + r;
                const float* ctr = ctab + t * 32;
                const float* str = stab + t * 32;
                #pragma unroll
                for (int nj = 0; nj < 2; ++nj) {
                    int i = nj * 16 + l15;
                    float c = ctr[i], s = str[i];
                    float x1 = acc[mi][nj][r], x2 = acc[mi][nj + 2][r];
                    dst[(size_t)t * 64 + i]      = f2bf(x1 * c - x2 * s);
                    dst[(size_t)t * 64 + 32 + i] = f2bf(x1 * s + x2 * c);
                }
            }
    } else {
        #pragma unroll
        for (int mi = 0; mi < 4; ++mi)
            #pragma unroll
            for (int nj = 0; nj < 4; ++nj) {
                int cg = nloc + wc * 64 + nj * 16 + l15;
                int hh = cg >> 7, pr = (cg >> 6) & 1, d = cg & 63;
                int tb = rb + wr * 64 + mi * 16 + quad * 4;
                ushort_t* dst = (pr ? v2T : v1T) + ((size_t)(hh * 64 + d)) * 2048 + tb;
                u64 pk = (u64)f2bf(acc[mi][nj][0])
                       | ((u64)f2bf(acc[mi][nj][1]) << 16)
                       | ((u64)f2bf(acc[mi][nj][2]) << 32)
                       | ((u64)f2bf(acc[mi][nj][3]) << 48);
                *(u64*)dst = pk;
            }
    }
}

// ---------------------------------------------------------------------------
// Register-direct merged attention: NO LDS staging of K/V (each MFMA fragment is
// a contiguous 16B global load), NO __syncthreads in the K-loop. Only LDS use is
// the per-wave P transpose (C-layout -> A-layout), which is wave-synchronous.
#define PSTRIDE 88

// S^T = K*Q^T for one attention; online softmax; P -> per-wave LDS. Returns alpha.
__device__ __forceinline__ float s_step(
    const ushort_t* __restrict__ kb, int ktoff, const short8* qb,
    ushort_t* __restrict__ pw, float& m_i, float& l_i,
    int quad, int l15, int row_l, bool diag)
{
    short8 kf[2][4];
    #pragma unroll
    for (int ks = 0; ks < 2; ++ks)
        #pragma unroll
        for (int j = 0; j < 4; ++j)
            kf[ks][j] = *(const short8*)(kb + ktoff + j * 1024 + ks * 32);
    f32x4 s[4];
    #pragma unroll
    for (int j = 0; j < 4; ++j) s[j] = (f32x4)0.0f;
    #pragma unroll
    for (int ks = 0; ks < 2; ++ks)
        #pragma unroll
        for (int j = 0; j < 4; ++j)
            s[j] = __builtin_amdgcn_mfma_f32_16x16x32_bf16(kf[ks][j], qb[ks], s[j], 0, 0, 0);

    float pv[16];
    float mx = -1e30f;
    #pragma unroll
    for (int j = 0; j < 4; ++j)
        #pragma unroll
        for (int r = 0; r < 4; ++r) {
            float v = s[j][r] * 0.125f;
            if (diag) {
                int kp = j * 16 + quad * 4 + r;
                v = (kp <= row_l) ? v : -1e30f;
            }
            pv[j * 4 + r] = v;
            mx = fmaxf(mx, v);
        }
    mx = fmaxf(mx, __shfl_xor(mx, 16));
    mx = fmaxf(mx, __shfl_xor(mx, 32));
    float newm = fmaxf(m_i, mx);
    float alpha = __expf(m_i - newm);
    float sum = 0.0f;
    ushort_t pb[16];
    #pragma unroll
    for (int i = 0; i < 16; ++i) {
        float p = __expf(pv[i] - newm);
        sum += p;
        pb[i] = f2bf(p);
    }
    sum += __shfl_xor(sum, 16);
    sum += __shfl_xor(sum, 32);
    l_i = l_i * alpha + sum;
    m_i = newm;
    #pragma unroll
    for (int j = 0; j < 4; ++j) {
        u64 pk = (u64)pb[j * 4] | ((u64)pb[j * 4 + 1] << 16)
               | ((u64)pb[j * 4 + 2] << 32) | ((u64)pb[j * 4 + 3] << 48);
        *(u64*)(pw + l15 * PSTRIDE + j * 16 + quad * 4) = pk;
    }
    return alpha;
}

__global__ __launch_bounds__(256, 2) void attn_reg(
    const ushort_t* __restrict__ q1, const ushort_t* __restrict__ k1,
    const ushort_t* __restrict__ q2, const ushort_t* __restrict__ k2,
    const ushort_t* __restrict__ v1T, const ushort_t* __restrict__ v2T,
    float* __restrict__ X, const float* __restrict__ lam_ptr)
{
    __shared__ ushort_t Ps[4][2][16 * PSTRIDE];

    const int tid = threadIdx.x;
    const int w = tid >> 6, lane = tid & 63;
    const int quad = lane >> 4, l15 = lane & 15;
    const int h = blockIdx.y;
    const int qt = 31 - blockIdx.x;
    const float lam = lam_ptr[0];
    const int row_l = w * 16 + l15;

    // Q fragments direct from global (A/B fragment: lane(l15,quad) reads 16B)
    short8 qb1[2], qb2[2];
    {
        const ushort_t* q1p = q1 + ((size_t)h * 2048 + qt * 64 + w * 16 + l15) * 64 + quad * 8;
        const ushort_t* q2p = q2 + ((size_t)h * 2048 + qt * 64 + w * 16 + l15) * 64 + quad * 8;
        qb1[0] = *(const short8*)(q1p);      qb1[1] = *(const short8*)(q1p + 32);
        qb2[0] = *(const short8*)(q2p);      qb2[1] = *(const short8*)(q2p + 32);
    }

    // per-lane base pointers
    const ushort_t* kb1 = k1 + ((size_t)h * 2048 + l15) * 64 + quad * 8;
    const ushort_t* kb2 = k2 + ((size_t)h * 2048 + l15) * 64 + quad * 8;
    const ushort_t* vb1 = v1T + ((size_t)h * 64 + l15) * 2048 + quad * 8;
    const ushort_t* vb2 = v2T + ((size_t)h * 64 + l15) * 2048 + quad * 8;

    ushort_t* pw1 = &Ps[w][0][0];
    ushort_t* pw2 = &Ps[w][1][0];

    f32x4 O1[8], O2[8];
    #pragma unroll
    for (int i = 0; i < 8; ++i) { O1[i] = (f32x4)0.0f; O2[i] = (f32x4)0.0f; }
    float m1 = -1e30f, l1 = 0.0f, m2 = -1e30f, l2 = 0.0f;

    for (int kt = 0; kt <= qt; ++kt) {
        const int ktoff = kt * 4096;     // kt*64 rows * 64 elems
        const int vtoff = kt * 64;
        const bool diag = (kt == qt);

        float a1 = s_step(kb1, ktoff, qb1, pw1, m1, l1, quad, l15, row_l, diag);
        float a2 = s_step(kb2, ktoff, qb2, pw2, m2, l2, quad, l15, row_l, diag);

        // rescale O by alpha (alpha for qrow quad*4+r lives in lane quad*4+r)
        {
            float a10 = __shfl(a1, quad * 4 + 0), a11 = __shfl(a1, quad * 4 + 1);
            float a12 = __shfl(a1, quad * 4 + 2), a13 = __shfl(a1, quad * 4 + 3);
            float a20 = __shfl(a2, quad * 4 + 0), a21 = __shfl(a2, quad * 4 + 1);
            float a22 = __shfl(a2, quad * 4 + 2), a23 = __shfl(a2, quad * 4 + 3);
            #pragma unroll
            for (int nt = 0; nt < 8; ++nt) {
                O1[nt][0] *= a10; O1[nt][1] *= a11; O1[nt][2] *= a12; O1[nt][3] *= a13;
                O2[nt][0] *= a20; O2[nt][1] *= a21; O2[nt][2] *= a22; O2[nt][3] *= a23;
            }
        }

        // O += P * V  (V fragments loaded once, used by both attentions)
        #pragma unroll
        for (int ks = 0; ks < 2; ++ks) {
            short8 pf1 = *(const short8*)(pw1 + l15 * PSTRIDE + ks * 32 + quad * 8);
            short8 pf2 = *(const short8*)(pw2 + l15 * PSTRIDE + ks * 32 + quad * 8);
            #pragma unroll
            for (int nt = 0; nt < 8; ++nt) {
                const ushort_t* vb = (nt < 4) ? vb1 : vb2;
                short8 vf = *(const short8*)(vb + (nt & 3) * 32768 + vtoff + ks * 32);
                O1[nt] = __builtin_amdgcn_mfma_f32_16x16x32_bf16(pf1, vf, O1[nt], 0, 0, 0);
                O2[nt] = __builtin_amdgcn_mfma_f32_16x16x32_bf16(pf2, vf, O2[nt], 0, 0, 0);
            }
        }
    }

    // epilogue: X = o1/l1 - lam * o2/l2
    float r10 = 1.0f / __shfl(l1, quad * 4 + 0);
    float r11 = 1.0f / __shfl(l1, quad * 4 + 1);
    float r12 = 1.0f / __shfl(l1, quad * 4 + 2);
    float r13 = 1.0f / __shfl(l1, quad * 4 + 3);
    float r20 = lam / __shfl(l2, quad * 4 + 0);
    float r21 = lam / __shfl(l2, quad * 4 + 1);
    float r22 = lam / __shfl(l2, quad * 4 + 2);
    float r23 = lam / __shfl(l2, quad * 4 + 3);
    int tb = qt * 64 + w * 16 + quad * 4;
    #pragma unroll
    for (int nt = 0; nt < 8; ++nt) {
        int col = h * 128 + nt * 16 + l15;
        X[(size_t)(tb + 0) * 2048 + col] = O1[nt][0] * r10 - O2[nt][0] * r20;
        X[(size_t)(tb + 1) * 2048 + col] = O1[nt][1] * r11 - O2[nt][1] * r21;
        X[(size_t)(tb + 2) * 2048 + col] = O1[nt][2] * r12 - O2[nt][2] * r22;
        X[(size_t)(tb + 3) * 2048 + col] = O1[nt][3] * r13 - O2[nt][3] * r23;
    }
}

// ---------------------------------------------------------------------------
// LDS-tiled truncated circular conv along t (129 taps); g[j]=g(tau=j-64)
__global__ __launch_bounds__(256) void conv_t(
    const float* __restrict__ X, const float* __restrict__ g, float* __restrict__ Y)
{
    __shared__ float Xs[192 * 64];
    __shared__ float gs[129];
    const int tid = threadIdx.x;
    const int c0 = blockIdx.x * 64, t0 = blockIdx.y * 64;
    const int c = tid & 63, tg = tid >> 6;
    for (int j = tg; j < 192; j += 4)
        Xs[j * 64 + c] = X[(size_t)((t0 - 64 + j) & 2047) * 2048 + c0 + c];
    if (tid < 129) gs[tid] = g[tid];
    __syncthreads();
    float accv[16];
    #pragma unroll
    for (int i = 0; i < 16; ++i) accv[i] = 0.0f;
    const int tl0 = tg * 16;
    for (int tap = 0; tap < 129; ++tap) {
        float gv = gs[tap];
        int base = (tl0 + 128 - tap) * 64 + c;
        #pragma unroll
        for (int i = 0; i < 16; ++i) accv[i] += gv * Xs[base + i * 64];
    }
    #pragma unroll
    for (int i = 0; i < 16; ++i)
        Y[(size_t)(t0 + tl0 + i) * 2048 + c0 + c] = accv[i];
}

// RMSNorm over 128 per (t,h); writes bf16 for the final GEMM
__global__ __launch_bounds__(64) void rms_bf(
    const float* __restrict__ Y, const float* __restrict__ wgt, ushort_t* __restrict__ yb)
{
    int grp = blockIdx.x;
    int t = grp >> 4, hh = grp & 15, l = threadIdx.x;
    size_t base = (size_t)t * 2048 + hh * 128;
    float a = Y[base + l];
    float b = Y[base + 64 + l];
    float ss = a * a + b * b;
    for (int off = 32; off; off >>= 1) ss += __shfl_down(ss, off);
    ss = __shfl(ss, 0);
    float r = rsqrtf(ss * (1.0f / 128.0f) + 1e-5f) * ONE_MINUS_LI;
    yb[base + l]      = f2bf(a * r * wgt[l]);
    yb[base + 64 + l] = f2bf(b * r * wgt[64 + l]);
}

// ---------------------------------------------------------------------------
// Final GEMM: 64x128 tile (grid 512 -> 2 blocks/CU). out = ybf * WoutT^T, fp32 out.
__global__ __launch_bounds__(256) void gemm_out(
    const ushort_t* __restrict__ A, const ushort_t* __restrict__ BT,
    float* __restrict__ C)
{
    __shared__ ushort_t As[4096];
    __shared__ ushort_t Bs[8192];
    const int tid = threadIdx.x;
    const int w = tid >> 6, lane = tid & 63;
    const int quad = lane >> 4, l15 = lane & 15;
    const int wr = w >> 1, wc = w & 1;
    const int rb = blockIdx.y * 64, cb = blockIdx.x * 128;

    f32x4 acc[2][4];
    #pragma unroll
    for (int i = 0; i < 2; ++i)
        #pragma unroll
        for (int j = 0; j < 4; ++j) acc[i][j] = (f32x4)0.0f;

    for (int k0 = 0; k0 < 2048; k0 += 64) {
        #pragma unroll
        for (int u = 0; u < 2; ++u) {
            int off = (w * 2 + u) * 512;
            int Lc = (off >> 3) + lane;
            int row = Lc >> 3, cc = (Lc & 7) ^ (row & 7);
            gld16(As + off, A + (size_t)(rb + row) * 2048 + k0 + cc * 8);
        }
        #pragma unroll
        for (int u = 0; u < 4; ++u) {
            int off = (w * 4 + u) * 512;
            int Lc = (off >> 3) + lane;
            int row = Lc >> 3, cc = (Lc & 7) ^ (row & 7);
            gld16(Bs + off, BT + (size_t)(cb + row) * 2048 + k0 + cc * 8);
        }
        __syncthreads();
        #pragma unroll
        for (int ks = 0; ks < 2; ++ks) {
            short8 af[2], bfr[4];
            #pragma unroll
            for (int mi = 0; mi < 2; ++mi) {
                int r = wr * 32 + mi * 16 + l15;
                af[mi] = *(const short8*)(As + r * 64 + ((ks * 4 + quad) ^ (r & 7)) * 8);
            }
            #pragma unroll
            for (int nj = 0; nj < 4; ++nj) {
                int r = wc * 64 + nj * 16 + l15;
                bfr[nj] = *(const short8*)(Bs + r * 64 + ((ks * 4 + quad) ^ (r & 7)) * 8);
            }
            #pragma unroll
            for (int mi = 0; mi < 2; ++mi)
                #pragma unroll
                for (int nj = 0; nj < 4; ++nj)
                    acc[mi][nj] = __builtin_amdgcn_mfma_f32_16x16x32_bf16(
                        af[mi], bfr[nj], acc[mi][nj], 0, 0, 0);
        }
        __syncthreads();
    }

    #pragma unroll
    for (int mi = 0; mi < 2; ++mi)
        #pragma unroll
        for (int nj = 0; nj < 4; ++nj) {
            int cg = cb + wc * 64 + nj * 16 + l15;
            #pragma unroll
            for (int r = 0; r < 4; ++r) {
                int t = rb + wr * 32 + mi * 16 + quad * 4 + r;
                C[(size_t)t * 2048 + cg] = acc[mi][nj][r];
            }
        }
}

// ---------------------------------------------------------------------------
extern "C" void kernel_launch(void* const* d_in, const int* in_sizes, int n_in,
                              void* d_out, int out_size, void* d_ws, size_t ws_size,
                              hipStream_t stream)
{
    const float* query = (const float*)d_in[0];
    const float* Wq    = (const float*)d_in[1];
    const float* Wk    = (const float*)d_in[2];
    const float* Wv    = (const float*)d_in[3];
    const float* Wout  = (const float*)d_in[4];
    const float* lq1   = (const float*)d_in[5];
    const float* lk1   = (const float*)d_in[6];
    const float* lq2   = (const float*)d_in[7];
    const float* lk2   = (const float*)d_in[8];
    const float* rmsw  = (const float*)d_in[9];
    float* out = (float*)d_out;

    const size_t MB = 1ull << 20;
    char* W = (char*)d_ws;
    ushort_t* WqT   = (ushort_t*)(W + 0 * MB);   // WqT/WkT/WvT contiguous: 24MB block
    ushort_t* WkT   = (ushort_t*)(W + 8 * MB);
    ushort_t* WvT   = (ushort_t*)(W + 16 * MB);
    ushort_t* WoutT = (ushort_t*)(W + 24 * MB);
    ushort_t* qb    = (ushort_t*)(W + 32 * MB);
    ushort_t* q1    = (ushort_t*)(W + 40 * MB);
    ushort_t* q2    = (ushort_t*)(W + 44 * MB);
    ushort_t* k1    = (ushort_t*)(W + 48 * MB);
    ushort_t* k2    = (ushort_t*)(W + 52 * MB);
    ushort_t* v1T   = (ushort_t*)(W + 56 * MB);
    ushort_t* v2T   = (ushort_t*)(W + 60 * MB);
    float*    X     = (float*)   (W + 64 * MB);
    float*    Y     = (float*)   (W + 32 * MB);  // aliases qb/q1/q2 (dead by conv time)
    ushort_t* ybf   = (ushort_t*)(W + 48 * MB);  // aliases k1/k2 (dead by rms time)
    float*    ctab  = (float*)   (W + 80 * MB);
    float*    stab  = (float*)   (W + 80 * MB + 256 * 1024);
    float*    gbuf  = (float*)   (W + 80 * MB + 512 * 1024);
    float*    lam   = (float*)   (W + 80 * MB + 520 * 1024);

    lambda_kernel<<<1, 64, 0, stream>>>(lq1, lk1, lq2, lk2, lam);
    gfilt_kernel<<<129, 256, 0, stream>>>(gbuf);
    rottab<<<256, 256, 0, stream>>>(ctab, stab);
    cvt_bf16<<<2048, 256, 0, stream>>>(query, qb);
    wtrans<<<dim3(32, 32, 4), 256, 0, stream>>>(Wq, Wk, Wv, Wout, WqT, WkT, WvT, WoutT);

    gemm_qkv<<<dim3(48, 16), 256, 0, stream>>>(qb, WqT, q1, q2, k1, k2, v1T, v2T, ctab, stab);

    attn_reg<<<dim3(32, 16), 256, 0, stream>>>(q1, k1, q2, k2, v1T, v2T, X, lam);

    conv_t<<<dim3(32, 32), 256, 0, stream>>>(X, gbuf, Y);
    rms_bf<<<32768, 64, 0, stream>>>(Y, rmsw, ybf);

    gemm_out<<<dim3(16, 32), 256, 0, stream>>>(ybf, WoutT, out);
}

// Round 6
// 366.159 us; speedup vs baseline: 1.3609x; 1.3609x over previous
//
#include <hip/hip_runtime.h>
#include <math.h>

#define LAMBDA_INIT_F 0.7836057665316245f
#define ONE_MINUS_LI  0.2163942334683755f

typedef unsigned short ushort_t;
typedef unsigned int   uint32;
typedef unsigned long long u64;
typedef __attribute__((ext_vector_type(8))) short short8;
typedef __attribute__((ext_vector_type(4))) float f32x4;

// float -> bf16 (RNE)
__device__ __forceinline__ ushort_t f2bf(float f) {
    union { float f; uint32 u; } x; x.f = f;
    uint32 r = (x.u + 0x7fffu + ((x.u >> 16) & 1u)) >> 16;
    return (ushort_t)r;
}

// async global->LDS, 16B per lane. lds must be wave-uniform base; HW adds lane*16.
__device__ __forceinline__ void gld16(ushort_t* lds, const ushort_t* g) {
    __builtin_amdgcn_global_load_lds(
        (const __attribute__((address_space(1))) uint32*)g,
        (__attribute__((address_space(3))) uint32*)lds,
        16, 0, 0);
}

// ---------------------------------------------------------------------------
__global__ __launch_bounds__(64) void lambda_kernel(
    const float* __restrict__ lq1, const float* __restrict__ lk1,
    const float* __restrict__ lq2, const float* __restrict__ lk2,
    float* __restrict__ lam)
{
    int l = threadIdx.x;
    float p1 = lq1[l] * lk1[l];
    float p2 = lq2[l] * lk2[l];
    for (int off = 32; off; off >>= 1) {
        p1 += __shfl_down(p1, off);
        p2 += __shfl_down(p2, off);
    }
    if (l == 0) lam[0] = expf(p1) - expf(p2) + LAMBDA_INIT_F;
}

// g[j] = irfft(gaussian filter)[tau=j-64], j in [0,129). Parallel k-sum.
__global__ __launch_bounds__(256) void gfilt_kernel(float* __restrict__ g)
{
    __shared__ float red[4];
    const int j = blockIdx.x;            // 0..128
    int tau = j - 64;
    int ta = tau < 0 ? -tau : tau;       // cos is even
    const int tid = threadIdx.x;
    float acc = 0.0f;
    for (int k = tid; k <= 1024; k += 256) {
        float w = (k == 0 || k == 1024) ? 1.0f : 2.0f;
        float r = (float)k * (1.0f / 153.6f);
        float f = expf(-0.5f * r * r);
        int m = (k * ta) & 2047;
        float ang = (float)m * 3.0679615757712823e-3f;
        acc += w * f * cosf(ang);
    }
    for (int off = 32; off; off >>= 1) acc += __shfl_down(acc, off);
    if ((tid & 63) == 0) red[tid >> 6] = acc;
    __syncthreads();
    if (tid == 0)
        g[j] = (red[0] + red[1] + red[2] + red[3]) * (1.0f / 2048.0f);
}

// rotary tables: ct/st[t*32 + i] = cos/sin(t * 10000^(-i/32))
__global__ __launch_bounds__(256) void rottab(float* __restrict__ ct, float* __restrict__ st)
{
    int id = blockIdx.x * 256 + threadIdx.x;
    int t = id >> 5, i = id & 31;
    double inv = exp(-0.28782313662425575 * (double)i);
    double a = (double)t * inv;
    ct[id] = (float)cos(a);
    st[id] = (float)sin(a);
}

// fp32 -> bf16 elementwise (8/thread)
__global__ __launch_bounds__(256) void cvt_bf16(const float* __restrict__ s, ushort_t* __restrict__ d)
{
    int i = (blockIdx.x * 256 + threadIdx.x) * 8;
    float4 a = *(const float4*)(s + i);
    float4 b = *(const float4*)(s + i + 4);
    uint4 pk;
    pk.x = (uint32)f2bf(a.x) | ((uint32)f2bf(a.y) << 16);
    pk.y = (uint32)f2bf(a.z) | ((uint32)f2bf(a.w) << 16);
    pk.z = (uint32)f2bf(b.x) | ((uint32)f2bf(b.y) << 16);
    pk.w = (uint32)f2bf(b.z) | ((uint32)f2bf(b.w) << 16);
    *(uint4*)(d + i) = pk;
}

// Transpose W[k][n] fp32 -> WT[n'][k] bf16. For z<2 (Wq,Wk) permute n within each
// 64-col head2 group: n' = head2*64 + (d&1)*32 + (d>>1)  (de-interleave rotary pairs)
__global__ __launch_bounds__(256) void wtrans(
    const float* __restrict__ Wq, const float* __restrict__ Wk,
    const float* __restrict__ Wv, const float* __restrict__ Wo,
    ushort_t* __restrict__ Tq, ushort_t* __restrict__ Tk,
    ushort_t* __restrict__ Tv, ushort_t* __restrict__ To)
{
    int z = blockIdx.z;
    const float* S = (z == 0) ? Wq : (z == 1) ? Wk : (z == 2) ? Wv : Wo;
    ushort_t* Dt = (z == 0) ? Tq : (z == 1) ? Tk : (z == 2) ? Tv : To;
    bool perm = (z < 2);
    __shared__ float Ls[64 * 65];
    const int tid = threadIdx.x;
    const int n0 = blockIdx.x * 64, k0 = blockIdx.y * 64;
    #pragma unroll
    for (int it = 0; it < 4; ++it) {
        int kk = it * 16 + (tid >> 4);
        int nn = (tid & 15) * 4;
        float4 v = *(const float4*)(S + (size_t)(k0 + kk) * 2048 + n0 + nn);
        Ls[(nn + 0) * 65 + kk] = v.x;
        Ls[(nn + 1) * 65 + kk] = v.y;
        Ls[(nn + 2) * 65 + kk] = v.z;
        Ls[(nn + 3) * 65 + kk] = v.w;
    }
    __syncthreads();
    int nl = tid >> 2, kc = (tid & 3) * 16;
    int ng = n0 + nl;
    int nd = perm ? ((ng & ~63) | ((ng & 1) << 5) | ((ng & 63) >> 1)) : ng;
    uint4 p0, p1;
    const float* row = Ls + nl * 65 + kc;
    p0.x = (uint32)f2bf(row[0])  | ((uint32)f2bf(row[1])  << 16);
    p0.y = (uint32)f2bf(row[2])  | ((uint32)f2bf(row[3])  << 16);
    p0.z = (uint32)f2bf(row[4])  | ((uint32)f2bf(row[5])  << 16);
    p0.w = (uint32)f2bf(row[6])  | ((uint32)f2bf(row[7])  << 16);
    p1.x = (uint32)f2bf(row[8])  | ((uint32)f2bf(row[9])  << 16);
    p1.y = (uint32)f2bf(row[10]) | ((uint32)f2bf(row[11]) << 16);
    p1.z = (uint32)f2bf(row[12]) | ((uint32)f2bf(row[13]) << 16);
    p1.w = (uint32)f2bf(row[14]) | ((uint32)f2bf(row[15]) << 16);
    *(uint4*)(Dt + (size_t)nd * 2048 + k0 + kc) = p0;
    *(uint4*)(Dt + (size_t)nd * 2048 + k0 + kc + 8) = p1;
}

// ---------------------------------------------------------------------------
// Fused QKV GEMM: C = qb(2048x2048) * WT^T where WT = [WqT;WkT;WvT] (6144x2048).
// Epilogue by n-region: 0 -> rotary -> q1/q2, 1 -> rotary -> k1/k2, 2 -> V^T.
__global__ __launch_bounds__(256) void gemm_qkv(
    const ushort_t* __restrict__ A, const ushort_t* __restrict__ WT,
    ushort_t* __restrict__ q1, ushort_t* __restrict__ q2,
    ushort_t* __restrict__ k1, ushort_t* __restrict__ k2,
    ushort_t* __restrict__ v1T, ushort_t* __restrict__ v2T,
    const float* __restrict__ ctab, const float* __restrict__ stab)
{
    __shared__ ushort_t As[8192];
    __shared__ ushort_t Bs[8192];
    const int tid = threadIdx.x;
    const int w = tid >> 6, lane = tid & 63;
    const int quad = lane >> 4, l15 = lane & 15;
    const int wr = w >> 1, wc = w & 1;
    const int rb = blockIdx.y * 128, cb = blockIdx.x * 128;

    f32x4 acc[4][4];
    #pragma unroll
    for (int i = 0; i < 4; ++i)
        #pragma unroll
        for (int j = 0; j < 4; ++j) acc[i][j] = (f32x4)0.0f;

    for (int k0 = 0; k0 < 2048; k0 += 64) {
        #pragma unroll
        for (int u = 0; u < 4; ++u) {
            int off = (w * 4 + u) * 512;
            int Lc = (off >> 3) + lane;
            int row = Lc >> 3, cc = (Lc & 7) ^ (row & 7);
            gld16(As + off, A + (size_t)(rb + row) * 2048 + k0 + cc * 8);
            gld16(Bs + off, WT + (size_t)(cb + row) * 2048 + k0 + cc * 8);
        }
        __syncthreads();
        #pragma unroll
        for (int ks = 0; ks < 2; ++ks) {
            short8 af[4], bfr[4];
            #pragma unroll
            for (int mi = 0; mi < 4; ++mi) {
                int r = wr * 64 + mi * 16 + l15;
                af[mi] = *(const short8*)(As + r * 64 + ((ks * 4 + quad) ^ (r & 7)) * 8);
            }
            #pragma unroll
            for (int nj = 0; nj < 4; ++nj) {
                int r = wc * 64 + nj * 16 + l15;
                bfr[nj] = *(const short8*)(Bs + r * 64 + ((ks * 4 + quad) ^ (r & 7)) * 8);
            }
            #pragma unroll
            for (int mi = 0; mi < 4; ++mi)
                #pragma unroll
                for (int nj = 0; nj < 4; ++nj)
                    acc[mi][nj] = __builtin_amdgcn_mfma_f32_16x16x32_bf16(
                        af[mi], bfr[nj], acc[mi][nj], 0, 0, 0);
        }
        __syncthreads();
    }

    const int region = cb >> 11;         // 0=Q, 1=K, 2=V
    const int nloc = cb & 2047;
    if (region < 2) {
        int head2 = (nloc + wc * 64) >> 6;
        ushort_t* b1 = region ? k1 : q1;
        ushort_t* b2 = region ? k2 : q2;
        ushort_t* dst = ((head2 & 1) ? b2 : b1) + (size_t)(head2 >> 1) * 2048 * 64;
        #pragma unroll
        for (int mi = 0; mi < 4; ++mi)
            #pragma unroll
            for (int r = 0; r < 4; ++r) {
                int t = rb + wr * 64 + mi * 16 + quad * 4 + r;
                const float* ctr = ctab + t * 32;
                const float* str = stab + t * 32;
                #pragma unroll
                for (int nj = 0; nj < 2; ++nj) {
                    int i = nj * 16 + l15;
                    float c = ctr[i], s = str[i];
                    float x1 = acc[mi][nj][r], x2 = acc[mi][nj + 2][r];
                    dst[(size_t)t * 64 + i]      = f2bf(x1 * c - x2 * s);
                    dst[(size_t)t * 64 + 32 + i] = f2bf(x1 * s + x2 * c);
                }
            }
    } else {
        #pragma unroll
        for (int mi = 0; mi < 4; ++mi)
            #pragma unroll
            for (int nj = 0; nj < 4; ++nj) {
                int cg = nloc + wc * 64 + nj * 16 + l15;
                int hh = cg >> 7, pr = (cg >> 6) & 1, d = cg & 63;
                int tb = rb + wr * 64 + mi * 16 + quad * 4;
                ushort_t* dst = (pr ? v2T : v1T) + ((size_t)(hh * 64 + d)) * 2048 + tb;
                u64 pk = (u64)f2bf(acc[mi][nj][0])
                       | ((u64)f2bf(acc[mi][nj][1]) << 16)
                       | ((u64)f2bf(acc[mi][nj][2]) << 32)
                       | ((u64)f2bf(acc[mi][nj][3]) << 48);
                *(u64*)dst = pk;
            }
    }
}

// ---------------------------------------------------------------------------
// Pipelined merged attention: single LDS tile buffer (K1,K2,V1,V2 @ 8KB each),
// prefetch of tile kt+1 into REGISTERS at top of iter (plain global loads, no
// wait), compute kt from LDS (hides the load latency), then barrier ->
// ds_write regs -> barrier. No vmcnt(0)-before-compute stall.
#define PSTRIDE 88

__device__ __forceinline__ void attn_step(
    const ushort_t* __restrict__ Kb, const ushort_t* __restrict__ V1b,
    const ushort_t* __restrict__ V2b, ushort_t* __restrict__ pw,
    const short8* qb, f32x4* O, float& m_i, float& l_i,
    int quad, int l15, int row_l, bool diag)
{
    f32x4 s[4];
    #pragma unroll
    for (int j = 0; j < 4; ++j) s[j] = (f32x4)0.0f;
    #pragma unroll
    for (int ks = 0; ks < 2; ++ks)
        #pragma unroll
        for (int j = 0; j < 4; ++j) {
            int r = j * 16 + l15;
            short8 kf = *(const short8*)(Kb + r * 64 + ((ks * 4 + quad) ^ (r & 7)) * 8);
            s[j] = __builtin_amdgcn_mfma_f32_16x16x32_bf16(kf, qb[ks], s[j], 0, 0, 0);
        }
    float pv[16];
    float mx = -1e30f;
    #pragma unroll
    for (int j = 0; j < 4; ++j)
        #pragma unroll
        for (int r = 0; r < 4; ++r) {
            float v = s[j][r] * 0.125f;
            if (diag) {
                int kp = j * 16 + quad * 4 + r;
                v = (kp <= row_l) ? v : -1e30f;
            }
            pv[j * 4 + r] = v;
            mx = fmaxf(mx, v);
        }
    mx = fmaxf(mx, __shfl_xor(mx, 16));
    mx = fmaxf(mx, __shfl_xor(mx, 32));
    float newm = fmaxf(m_i, mx);
    float alpha = __expf(m_i - newm);
    float sum = 0.0f;
    ushort_t pb[16];
    #pragma unroll
    for (int i = 0; i < 16; ++i) {
        float p = __expf(pv[i] - newm);
        sum += p;
        pb[i] = f2bf(p);
    }
    sum += __shfl_xor(sum, 16);
    sum += __shfl_xor(sum, 32);
    l_i = l_i * alpha + sum;
    m_i = newm;
    #pragma unroll
    for (int j = 0; j < 4; ++j) {
        u64 pk = (u64)pb[j * 4] | ((u64)pb[j * 4 + 1] << 16)
               | ((u64)pb[j * 4 + 2] << 32) | ((u64)pb[j * 4 + 3] << 48);
        *(u64*)(pw + l15 * PSTRIDE + j * 16 + quad * 4) = pk;
    }
    float av0 = __shfl(alpha, quad * 4 + 0);
    float av1 = __shfl(alpha, quad * 4 + 1);
    float av2 = __shfl(alpha, quad * 4 + 2);
    float av3 = __shfl(alpha, quad * 4 + 3);
    #pragma unroll
    for (int nt = 0; nt < 8; ++nt) {
        O[nt][0] *= av0; O[nt][1] *= av1; O[nt][2] *= av2; O[nt][3] *= av3;
    }
    #pragma unroll
    for (int ks = 0; ks < 2; ++ks) {
        short8 pf = *(const short8*)(pw + l15 * PSTRIDE + ks * 32 + quad * 8);
        #pragma unroll
        for (int nt = 0; nt < 8; ++nt) {
            const ushort_t* Vs = (nt < 4) ? V1b : V2b;
            int d = (nt & 3) * 16 + l15;
            short8 vf = *(const short8*)(Vs + d * 64 + ((ks * 4 + quad) ^ (d & 7)) * 8);
            O[nt] = __builtin_amdgcn_mfma_f32_16x16x32_bf16(pf, vf, O[nt], 0, 0, 0);
        }
    }
}

__global__ __launch_bounds__(256) void attn_pipe(
    const ushort_t* __restrict__ q1, const ushort_t* __restrict__ k1,
    const ushort_t* __restrict__ q2, const ushort_t* __restrict__ k2,
    const ushort_t* __restrict__ v1T, const ushort_t* __restrict__ v2T,
    float* __restrict__ X, const float* __restrict__ lam_ptr)
{
    __shared__ ushort_t Tt[4][4096];    // K1,K2,V1,V2 current tile (swizzled chunks)
    __shared__ ushort_t Ps[4][2][16 * PSTRIDE];

    const int tid = threadIdx.x;
    const int w = tid >> 6, lane = tid & 63;
    const int quad = lane >> 4, l15 = lane & 15;
    const int b = blockIdx.x;
    const int h = b & 15;               // head -> fixed XCD (b%8 pattern): L2 locality
    const int qt = 31 - (b >> 4);       // heaviest qt for all heads dispatched first
    const float lam = lam_ptr[0];
    const int row_l = w * 16 + l15;

    const ushort_t* k1h = k1 + (size_t)h * 2048 * 64;
    const ushort_t* k2h = k2 + (size_t)h * 2048 * 64;
    const ushort_t* v1h = v1T + (size_t)h * 64 * 2048;
    const ushort_t* v2h = v2T + (size_t)h * 64 * 2048;

    // Q fragments direct from global
    short8 qb1[2], qb2[2];
    {
        const ushort_t* q1p = q1 + ((size_t)h * 2048 + qt * 64 + w * 16 + l15) * 64 + quad * 8;
        const ushort_t* q2p = q2 + ((size_t)h * 2048 + qt * 64 + w * 16 + l15) * 64 + quad * 8;
        qb1[0] = *(const short8*)(q1p);      qb1[1] = *(const short8*)(q1p + 32);
        qb2[0] = *(const short8*)(q2p);      qb2[1] = *(const short8*)(q2p + 32);
    }

    // staging chunk map: this thread owns chunks ci = tid*2+u (u=0,1) of each tile.
    // chunk ci holds global (row=ci>>3, cc=(ci&7)^(row&7)) -> LDS bytes [ci*16,+16)
    int ci[2], koff[2], voff[2];
    #pragma unroll
    for (int u = 0; u < 2; ++u) {
        ci[u] = tid * 2 + u;
        int row = ci[u] >> 3, cc = (ci[u] & 7) ^ (row & 7);
        koff[u] = row * 64 + cc * 8;     // K tile: row stride 64
        voff[u] = row * 2048 + cc * 8;   // V^T: row stride 2048
    }

    short8 sK1[2], sK2[2], sV1[2], sV2[2];

    // preload tile 0 -> regs -> LDS
    #pragma unroll
    for (int u = 0; u < 2; ++u) {
        sK1[u] = *(const short8*)(k1h + koff[u]);
        sK2[u] = *(const short8*)(k2h + koff[u]);
        sV1[u] = *(const short8*)(v1h + voff[u]);
        sV2[u] = *(const short8*)(v2h + voff[u]);
    }
    #pragma unroll
    for (int u = 0; u < 2; ++u) {
        *(short8*)(&Tt[0][ci[u] * 8]) = sK1[u];
        *(short8*)(&Tt[1][ci[u] * 8]) = sK2[u];
        *(short8*)(&Tt[2][ci[u] * 8]) = sV1[u];
        *(short8*)(&Tt[3][ci[u] * 8]) = sV2[u];
    }
    __syncthreads();

    f32x4 O1[8], O2[8];
    #pragma unroll
    for (int i = 0; i < 8; ++i) { O1[i] = (f32x4)0.0f; O2[i] = (f32x4)0.0f; }
    float m1 = -1e30f, l1 = 0.0f, m2 = -1e30f, l2 = 0.0f;

    for (int kt = 0; kt <= qt; ++kt) {
        if (kt < qt) {
            // issue prefetch of kt+1 (consumed only after the compute phase)
            int kb = (kt + 1) * 4096, vb = (kt + 1) * 64;
            #pragma unroll
            for (int u = 0; u < 2; ++u) {
                sK1[u] = *(const short8*)(k1h + kb + koff[u]);
                sK2[u] = *(const short8*)(k2h + kb + koff[u]);
                sV1[u] = *(const short8*)(v1h + vb + voff[u]);
                sV2[u] = *(const short8*)(v2h + vb + voff[u]);
            }
        }
        const bool diag = (kt == qt);
        attn_step(Tt[0], Tt[2], Tt[3], &Ps[w][0][0], qb1, O1, m1, l1, quad, l15, row_l, diag);
        attn_step(Tt[1], Tt[2], Tt[3], &Ps[w][1][0], qb2, O2, m2, l2, quad, l15, row_l, diag);
        __syncthreads();                 // all waves done reading Tt
        if (kt < qt) {
            #pragma unroll
            for (int u = 0; u < 2; ++u) {
                *(short8*)(&Tt[0][ci[u] * 8]) = sK1[u];
                *(short8*)(&Tt[1][ci[u] * 8]) = sK2[u];
                *(short8*)(&Tt[2][ci[u] * 8]) = sV1[u];
                *(short8*)(&Tt[3][ci[u] * 8]) = sV2[u];
            }
            __syncthreads();             // Tt ready for next iter
        }
    }

    // epilogue: X = o1/l1 - lam * o2/l2
    float r10 = 1.0f / __shfl(l1, quad * 4 + 0);
    float r11 = 1.0f / __shfl(l1, quad * 4 + 1);
    float r12 = 1.0f / __shfl(l1, quad * 4 + 2);
    float r13 = 1.0f / __shfl(l1, quad * 4 + 3);
    float r20 = lam / __shfl(l2, quad * 4 + 0);
    float r21 = lam / __shfl(l2, quad * 4 + 1);
    float r22 = lam / __shfl(l2, quad * 4 + 2);
    float r23 = lam / __shfl(l2, quad * 4 + 3);
    int tb = qt * 64 + w * 16 + quad * 4;
    #pragma unroll
    for (int nt = 0; nt < 8; ++nt) {
        int col = h * 128 + nt * 16 + l15;
        X[(size_t)(tb + 0) * 2048 + col] = O1[nt][0] * r10 - O2[nt][0] * r20;
        X[(size_t)(tb + 1) * 2048 + col] = O1[nt][1] * r11 - O2[nt][1] * r21;
        X[(size_t)(tb + 2) * 2048 + col] = O1[nt][2] * r12 - O2[nt][2] * r22;
        X[(size_t)(tb + 3) * 2048 + col] = O1[nt][3] * r13 - O2[nt][3] * r23;
    }
}

// ---------------------------------------------------------------------------
// LDS-tiled truncated circular conv along t (129 taps); g[j]=g(tau=j-64)
__global__ __launch_bounds__(256) void conv_t(
    const float* __restrict__ X, const float* __restrict__ g, float* __restrict__ Y)
{
    __shared__ float Xs[192 * 64];
    __shared__ float gs[129];
    const int tid = threadIdx.x;
    const int c0 = blockIdx.x * 64, t0 = blockIdx.y * 64;
    const int c = tid & 63, tg = tid >> 6;
    for (int j = tg; j < 192; j += 4)
        Xs[j * 64 + c] = X[(size_t)((t0 - 64 + j) & 2047) * 2048 + c0 + c];
    if (tid < 129) gs[tid] = g[tid];
    __syncthreads();
    float accv[16];
    #pragma unroll
    for (int i = 0; i < 16; ++i) accv[i] = 0.0f;
    const int tl0 = tg * 16;
    for (int tap = 0; tap < 129; ++tap) {
        float gv = gs[tap];
        int base = (tl0 + 128 - tap) * 64 + c;
        #pragma unroll
        for (int i = 0; i < 16; ++i) accv[i] += gv * Xs[base + i * 64];
    }
    #pragma unroll
    for (int i = 0; i < 16; ++i)
        Y[(size_t)(t0 + tl0 + i) * 2048 + c0 + c] = accv[i];
}

// RMSNorm over 128 per (t,h); writes bf16 for the final GEMM
__global__ __launch_bounds__(64) void rms_bf(
    const float* __restrict__ Y, const float* __restrict__ wgt, ushort_t* __restrict__ yb)
{
    int grp = blockIdx.x;
    int t = grp >> 4, hh = grp & 15, l = threadIdx.x;
    size_t base = (size_t)t * 2048 + hh * 128;
    float a = Y[base + l];
    float b = Y[base + 64 + l];
    float ss = a * a + b * b;
    for (int off = 32; off; off >>= 1) ss += __shfl_down(ss, off);
    ss = __shfl(ss, 0);
    float r = rsqrtf(ss * (1.0f / 128.0f) + 1e-5f) * ONE_MINUS_LI;
    yb[base + l]      = f2bf(a * r * wgt[l]);
    yb[base + 64 + l] = f2bf(b * r * wgt[64 + l]);
}

// ---------------------------------------------------------------------------
// Final GEMM: 64x128 tile (grid 512 -> 2 blocks/CU). out = ybf * WoutT^T, fp32 out.
__global__ __launch_bounds__(256) void gemm_out(
    const ushort_t* __restrict__ A, const ushort_t* __restrict__ BT,
    float* __restrict__ C)
{
    __shared__ ushort_t As[4096];
    __shared__ ushort_t Bs[8192];
    const int tid = threadIdx.x;
    const int w = tid >> 6, lane = tid & 63;
    const int quad = lane >> 4, l15 = lane & 15;
    const int wr = w >> 1, wc = w & 1;
    const int rb = blockIdx.y * 64, cb = blockIdx.x * 128;

    f32x4 acc[2][4];
    #pragma unroll
    for (int i = 0; i < 2; ++i)
        #pragma unroll
        for (int j = 0; j < 4; ++j) acc[i][j] = (f32x4)0.0f;

    for (int k0 = 0; k0 < 2048; k0 += 64) {
        #pragma unroll
        for (int u = 0; u < 2; ++u) {
            int off = (w * 2 + u) * 512;
            int Lc = (off >> 3) + lane;
            int row = Lc >> 3, cc = (Lc & 7) ^ (row & 7);
            gld16(As + off, A + (size_t)(rb + row) * 2048 + k0 + cc * 8);
        }
        #pragma unroll
        for (int u = 0; u < 4; ++u) {
            int off = (w * 4 + u) * 512;
            int Lc = (off >> 3) + lane;
            int row = Lc >> 3, cc = (Lc & 7) ^ (row & 7);
            gld16(Bs + off, BT + (size_t)(cb + row) * 2048 + k0 + cc * 8);
        }
        __syncthreads();
        #pragma unroll
        for (int ks = 0; ks < 2; ++ks) {
            short8 af[2], bfr[4];
            #pragma unroll
            for (int mi = 0; mi < 2; ++mi) {
                int r = wr * 32 + mi * 16 + l15;
                af[mi] = *(const short8*)(As + r * 64 + ((ks * 4 + quad) ^ (r & 7)) * 8);
            }
            #pragma unroll
            for (int nj = 0; nj < 4; ++nj) {
                int r = wc * 64 + nj * 16 + l15;
                bfr[nj] = *(const short8*)(Bs + r * 64 + ((ks * 4 + quad) ^ (r & 7)) * 8);
            }
            #pragma unroll
            for (int mi = 0; mi < 2; ++mi)
                #pragma unroll
                for (int nj = 0; nj < 4; ++nj)
                    acc[mi][nj] = __builtin_amdgcn_mfma_f32_16x16x32_bf16(
                        af[mi], bfr[nj], acc[mi][nj], 0, 0, 0);
        }
        __syncthreads();
    }

    #pragma unroll
    for (int mi = 0; mi < 2; ++mi)
        #pragma unroll
        for (int nj = 0; nj < 4; ++nj) {
            int cg = cb + wc * 64 + nj * 16 + l15;
            #pragma unroll
            for (int r = 0; r < 4; ++r) {
                int t = rb + wr * 32 + mi * 16 + quad * 4 + r;
                C[(size_t)t * 2048 + cg] = acc[mi][nj][r];
            }
        }
}

// ---------------------------------------------------------------------------
extern "C" void kernel_launch(void* const* d_in, const int* in_sizes, int n_in,
                              void* d_out, int out_size, void* d_ws, size_t ws_size,
                              hipStream_t stream)
{
    const float* query = (const float*)d_in[0];
    const float* Wq    = (const float*)d_in[1];
    const float* Wk    = (const float*)d_in[2];
    const float* Wv    = (const float*)d_in[3];
    const float* Wout  = (const float*)d_in[4];
    const float* lq1   = (const float*)d_in[5];
    const float* lk1   = (const float*)d_in[6];
    const float* lq2   = (const float*)d_in[7];
    const float* lk2   = (const float*)d_in[8];
    const float* rmsw  = (const float*)d_in[9];
    float* out = (float*)d_out;

    const size_t MB = 1ull << 20;
    char* W = (char*)d_ws;
    ushort_t* WqT   = (ushort_t*)(W + 0 * MB);   // WqT/WkT/WvT contiguous: 24MB block
    ushort_t* WkT   = (ushort_t*)(W + 8 * MB);
    ushort_t* WvT   = (ushort_t*)(W + 16 * MB);
    ushort_t* WoutT = (ushort_t*)(W + 24 * MB);
    ushort_t* qb    = (ushort_t*)(W + 32 * MB);
    ushort_t* q1    = (ushort_t*)(W + 40 * MB);
    ushort_t* q2    = (ushort_t*)(W + 44 * MB);
    ushort_t* k1    = (ushort_t*)(W + 48 * MB);
    ushort_t* k2    = (ushort_t*)(W + 52 * MB);
    ushort_t* v1T   = (ushort_t*)(W + 56 * MB);
    ushort_t* v2T   = (ushort_t*)(W + 60 * MB);
    float*    X     = (float*)   (W + 64 * MB);
    float*    Y     = (float*)   (W + 32 * MB);  // aliases qb/q1/q2 (dead by conv time)
    ushort_t* ybf   = (ushort_t*)(W + 48 * MB);  // aliases k1/k2 (dead by rms time)
    float*    ctab  = (float*)   (W + 80 * MB);
    float*    stab  = (float*)   (W + 80 * MB + 256 * 1024);
    float*    gbuf  = (float*)   (W + 80 * MB + 512 * 1024);
    float*    lam   = (float*)   (W + 80 * MB + 520 * 1024);

    lambda_kernel<<<1, 64, 0, stream>>>(lq1, lk1, lq2, lk2, lam);
    gfilt_kernel<<<129, 256, 0, stream>>>(gbuf);
    rottab<<<256, 256, 0, stream>>>(ctab, stab);
    cvt_bf16<<<2048, 256, 0, stream>>>(query, qb);
    wtrans<<<dim3(32, 32, 4), 256, 0, stream>>>(Wq, Wk, Wv, Wout, WqT, WkT, WvT, WoutT);

    gemm_qkv<<<dim3(48, 16), 256, 0, stream>>>(qb, WqT, q1, q2, k1, k2, v1T, v2T, ctab, stab);

    attn_pipe<<<512, 256, 0, stream>>>(q1, k1, q2, k2, v1T, v2T, X, lam);

    conv_t<<<dim3(32, 32), 256, 0, stream>>>(X, gbuf, Y);
    rms_bf<<<32768, 64, 0, stream>>>(Y, rmsw, ybf);

    gemm_out<<<dim3(16, 32), 256, 0, stream>>>(ybf, WoutT, out);
}